// Round 4
// baseline (72.632 us; speedup 1.0000x reference)
//
#include <hip/hip_runtime.h>

#define BN 512
#define DIM 128
#define TMARGIN 0.3f
#define NT 1024
#define NW 16     // waves per block
#define NBLK 256  // 2 anchors per block, 1 block/CU
#define BIGF 1e30f

#define FMA4(ACC, U, V)                                                \
    ACC.x += U.x * V.x; ACC.y += U.y * V.y;                            \
    ACC.z += U.z * V.z; ACC.w += U.w * V.w;

__device__ __forceinline__ float hsum4(float4 v) {
    return (v.x + v.y) + (v.z + v.w);
}

// ---------------------------------------------------------------------------
// SINGLE dispatch. The finalize kernel is replaced by a last-block-done
// ticket held in MODULE globals (our allocation -> immune to the harness's
// per-iteration workspace re-poison, unlike a workspace ticket; initialized
// once at module load; the finishing block resets it for the next graph
// replay). Cross-block visibility uses agent-scope atomics (G16): per-XCD
// L2s are not coherent, so partials are release-stored / acquire-loaded.
//
// Round-2 lesson: cooperative grid.sync() costs 25-30 us in-kernel AND
// loses the graph fast-path (112 us total). The ticket gives single-dispatch
// with a plain capturable launch instead.
//
// Retained (all measured wins):
//  * NT=1024: 16 waves, 4 waves/SIMD (round-3: -2.3 us)
//  * anchors in registers (kl-slice)
//  * negative mask folded into drow (1e30 sentinel; no labels in Phase B)
//  * positive DISTANCES compacted inline in Phase A
//  * epilogue reduction in the EXACT order of the old finalize kernel
//    (lane-stride + shuffle tree) -> bit-identical output
// ---------------------------------------------------------------------------
__device__ float g_psum[NBLK];
__device__ float g_pcnt[NBLK];
__device__ int   g_ticket = 0;   // module-load init; self-reset each run

__global__ __launch_bounds__(NT, 4) void triplet_fused_kernel(
        const float* __restrict__ emb,
        const int* __restrict__ labels,
        float* __restrict__ out) {   // [1]
    const int ia   = blockIdx.x;         // anchor A
    const int ib   = blockIdx.x + NBLK;  // anchor B
    const int tid  = threadIdx.x;
    const int lane = tid & 63;
    const int wave = tid >> 6;
    const int rl   = lane >> 2;   // row-in-group 0..15
    const int kl   = lane & 3;    // k-lane 0..3

    __shared__ float drowA[BN], drowB[BN];   // negatives-only distance rows
    __shared__ float pdA[BN], pdB[BN];       // positive distances (compact)
    __shared__ int   nposA, nposB;
    __shared__ float wsum[NW];
    __shared__ int   wcnt[NW];
    __shared__ int   slast;

    const float4* emb4 = (const float4*)emb;
    const int liA = labels[ia];
    const int liB = labels[ib];

    // --- anchor fragments in registers (kl-slice only) --------------------
    float4 ra[8], rb[8];
#pragma unroll
    for (int q = 0; q < 8; ++q) {
        ra[q] = emb4[(size_t)ia * 32 + kl + 4 * q];
        rb[q] = emb4[(size_t)ib * 32 + kl + 4 * q];
    }
    // squared norms: per-thread partial over the kl-slice, then 4-lane sum
    float4 sa = {0,0,0,0}, sb = {0,0,0,0};
#pragma unroll
    for (int q = 0; q < 8; ++q) { FMA4(sa, ra[q], ra[q]); FMA4(sb, rb[q], rb[q]); }
    float sqA = hsum4(sa), sqB = hsum4(sb);
    sqA += __shfl_xor(sqA, 1); sqA += __shfl_xor(sqA, 2);
    sqB += __shfl_xor(sqB, 1); sqB += __shfl_xor(sqB, 2);

    if (tid == 0) { nposA = 0; nposB = 0; }
    __syncthreads();

    // ---------------- Phase A: both dist rows, one pass over emb ----------
    // 16 waves x 16 rows/iter; 4 lanes per row, 64 B contiguous per group.
#pragma unroll
    for (int c = 0; c < 2; ++c) {
        const int r = c * 256 + wave * 16 + rl;
        float4 da = {0,0,0,0}, db = {0,0,0,0}, qq = {0,0,0,0};
#pragma unroll
        for (int q = 0; q < 8; ++q) {
            const float4 v = emb4[(size_t)r * 32 + kl + 4 * q];
            FMA4(da, ra[q], v);
            FMA4(db, rb[q], v);
            FMA4(qq, v, v);
        }
        float dotA = hsum4(da), dotB = hsum4(db), sqj = hsum4(qq);
        dotA += __shfl_down(dotA, 1); dotA += __shfl_down(dotA, 2);
        dotB += __shfl_down(dotB, 1); dotB += __shfl_down(dotB, 2);
        sqj  += __shfl_down(sqj, 1);  sqj  += __shfl_down(sqj, 2);
        if (kl == 0) {
            const int   lr = labels[r];
            const float dA = sqrtf(fmaxf(sqA + sqj - 2.f * dotA, 1e-12f));
            const float dB = sqrtf(fmaxf(sqB + sqj - 2.f * dotB, 1e-12f));
            const bool  eqA = (lr == liA), eqB = (lr == liB);
            drowA[r] = eqA ? BIGF : dA;     // self has eqA -> excluded too
            drowB[r] = eqB ? BIGF : dB;
            if (eqA && r != ia) { int p = atomicAdd(&nposA, 1); pdA[p] = dA; }
            if (eqB && r != ib) { int p = atomicAdd(&nposB, 1); pdB[p] = dB; }
        }
    }
    __syncthreads();

    // ---------------- Phase B: waves 0-7 anchor A, 8-15 anchor B ----------
    const int grp  = wave >> 3;             // 0: A, 1: B
    const int wsub = wave & 7;
    const float* drow = grp ? drowB : drowA;
    const float* pd   = grp ? pdB   : pdA;
    const int    npos = grp ? nposB : nposA;

    // min over negatives (BIGF is identity); has_neg == (mn < 1e29)
    float mn = BIGF;
#pragma unroll
    for (int kk = 0; kk < BN / 64; ++kk)
        mn = fminf(mn, drow[lane + 64 * kk]);
#pragma unroll
    for (int off = 32; off; off >>= 1)
        mn = fminf(mn, __shfl_xor(mn, off));

    float lsum = 0.f;
    int   lcnt = 0;
    if (mn < 1e29f) {
        for (int p = wsub; p < npos; p += 8) {
            const float dap = pd[p];
            const float hi  = dap + TMARGIN;
            float smax = -BIGF;
#pragma unroll
            for (int kk = 0; kk < BN / 64; ++kk) {
                const float dan = drow[lane + 64 * kk];
                if (dan > dap && dan < hi) smax = fmaxf(smax, dan);
            }
#pragma unroll
            for (int off = 32; off; off >>= 1)
                smax = fmaxf(smax, __shfl_xor(smax, off));
            const float dneg = (smax > -1e29f) ? smax : mn;
            lsum += fmaxf(dap - dneg + TMARGIN, 0.f);
            lcnt += 1;
        }
    }
    if (lane == 0) { wsum[wave] = lsum; wcnt[wave] = lcnt; }
    __syncthreads();

    // ---- publish partial (agent scope), take a ticket ---------------------
    if (tid == 0) {
        float s = 0.f;
        int   c = 0;
#pragma unroll
        for (int w = 0; w < NW; ++w) { s += wsum[w]; c += wcnt[w]; }
        __hip_atomic_store(&g_psum[blockIdx.x], s, __ATOMIC_RELEASE,
                           __HIP_MEMORY_SCOPE_AGENT);
        __hip_atomic_store(&g_pcnt[blockIdx.x], (float)c, __ATOMIC_RELEASE,
                           __HIP_MEMORY_SCOPE_AGENT);
        const int old = __hip_atomic_fetch_add(&g_ticket, 1, __ATOMIC_ACQ_REL,
                                               __HIP_MEMORY_SCOPE_AGENT);
        slast = (old == NBLK - 1);
    }
    __syncthreads();

    // ---- last block: reduce 256 slots (same order as old finalize) -------
    if (slast && wave == 0) {
        float s = 0.f, c = 0.f;
#pragma unroll
        for (int i = 0; i < NBLK / 64; ++i) {
            s += __hip_atomic_load(&g_psum[lane + 64 * i], __ATOMIC_ACQUIRE,
                                   __HIP_MEMORY_SCOPE_AGENT);
            c += __hip_atomic_load(&g_pcnt[lane + 64 * i], __ATOMIC_ACQUIRE,
                                   __HIP_MEMORY_SCOPE_AGENT);
        }
#pragma unroll
        for (int off = 32; off; off >>= 1) {
            s += __shfl_xor(s, off);
            c += __shfl_xor(c, off);
        }
        if (lane == 0) {
            out[0] = (c > 0.f) ? (s / fmaxf(c, 1.f)) : 0.f;
            // reset for next graph replay (module global survives re-poison)
            __hip_atomic_store(&g_ticket, 0, __ATOMIC_RELEASE,
                               __HIP_MEMORY_SCOPE_AGENT);
        }
    }
}

extern "C" void kernel_launch(void* const* d_in, const int* in_sizes, int n_in,
                              void* d_out, int out_size, void* d_ws, size_t ws_size,
                              hipStream_t stream) {
    const float* emb    = (const float*)d_in[0];
    const int*   labels = (const int*)d_in[1];
    float*       out    = (float*)d_out;
    (void)d_ws; (void)ws_size;   // workspace unused (ticket lives in module globals)

    triplet_fused_kernel<<<NBLK, NT, 0, stream>>>(emb, labels, out);
}

// Round 5
// 65.877 us; speedup vs baseline: 1.1025x; 1.1025x over previous
//
#include <hip/hip_runtime.h>

#define BN 512
#define DIM 128
#define TMARGIN 0.3f
#define NT 1024
#define NW 16     // waves per block
#define NBLK 128  // 4 anchors per block, 1 block/CU on 128 CUs
#define BIGF 1e30f

#define FMA4(ACC, U, V)                                                \
    ACC.x += U.x * V.x; ACC.y += U.y * V.y;                            \
    ACC.z += U.z * V.z; ACC.w += U.w * V.w;

__device__ __forceinline__ float hsum4(float4 v) {
    return (v.x + v.y) + (v.z + v.w);
}

// ---------------------------------------------------------------------------
// Two-kernel structure (measured best; single-dispatch attempts both lost:
// grid.sync +25us r2, contended ticket +9us r4).
//
// vs round-3 (63.9us): 4 ANCHORS PER BLOCK, 128 blocks.
// Invariant: per-block load bytes are fixed (512 rows x 256B = 256KB)
// regardless of layout -> more anchors/block is the only way to cut L2
// traffic. 128 blocks halves per-XCD L2 reads (8->4MB) and halves launch
// ramp; FMA-per-load rises 12->20 for better latency hiding at the same
// per-thread load depth (16).
// k-split widened to 8 lanes/row so the 4 anchor slices stay at 16 float4
// (~64 VGPR) -> fits the 128-VGPR cap for 4 waves/SIMD without spills.
//
// Retained: anchors in registers; negative mask folded into drow (1e30
// sentinel, no labels in Phase B); positive DISTANCES compacted inline;
// plain-store partials + 1-wave finalize.
// ---------------------------------------------------------------------------
__global__ __launch_bounds__(NT, 4) void triplet_fused_kernel(
        const float* __restrict__ emb,
        const int* __restrict__ labels,
        float* __restrict__ psum,    // [NBLK]
        float* __restrict__ pcnt) {  // [NBLK]
    const int i0   = blockIdx.x;           // anchor 0
    const int i1   = blockIdx.x + 128;     // anchor 1
    const int i2   = blockIdx.x + 256;     // anchor 2
    const int i3   = blockIdx.x + 384;     // anchor 3
    const int tid  = threadIdx.x;
    const int lane = tid & 63;
    const int wave = tid >> 6;
    const int rl   = lane >> 3;   // row-in-group 0..7
    const int kl   = lane & 7;    // k-lane 0..7

    __shared__ float drows[4][BN];   // negatives-only distance rows
    __shared__ float pds[4][BN];     // positive distances (compact)
    __shared__ int   nposArr[4];
    __shared__ float wsum[NW];
    __shared__ int   wcnt[NW];

    const float4* emb4 = (const float4*)emb;
    const int li0 = labels[i0];
    const int li1 = labels[i1];
    const int li2 = labels[i2];
    const int li3 = labels[i3];

    // --- anchor fragments in registers (kl-slice: 4 float4 per anchor) ----
    float4 r0[4], r1[4], r2[4], r3[4];
#pragma unroll
    for (int q = 0; q < 4; ++q) {
        r0[q] = emb4[(size_t)i0 * 32 + kl + 8 * q];
        r1[q] = emb4[(size_t)i1 * 32 + kl + 8 * q];
        r2[q] = emb4[(size_t)i2 * 32 + kl + 8 * q];
        r3[q] = emb4[(size_t)i3 * 32 + kl + 8 * q];
    }
    // squared norms: per-thread partial over the kl-slice, then 8-lane sum
    float4 s0 = {0,0,0,0}, s1 = {0,0,0,0}, s2 = {0,0,0,0}, s3 = {0,0,0,0};
#pragma unroll
    for (int q = 0; q < 4; ++q) {
        FMA4(s0, r0[q], r0[q]); FMA4(s1, r1[q], r1[q]);
        FMA4(s2, r2[q], r2[q]); FMA4(s3, r3[q], r3[q]);
    }
    float sq0 = hsum4(s0), sq1 = hsum4(s1), sq2 = hsum4(s2), sq3 = hsum4(s3);
#pragma unroll
    for (int off = 1; off < 8; off <<= 1) {
        sq0 += __shfl_xor(sq0, off); sq1 += __shfl_xor(sq1, off);
        sq2 += __shfl_xor(sq2, off); sq3 += __shfl_xor(sq3, off);
    }

    if (tid < 4) nposArr[tid] = 0;
    __syncthreads();

    // ---------------- Phase A: 4 dist rows, one pass over emb -------------
    // 16 waves x 8 rows/iter; 8 lanes per row, 128 B contiguous per group.
#pragma unroll
    for (int c = 0; c < 4; ++c) {
        const int r = c * 128 + wave * 8 + rl;
        float4 d0 = {0,0,0,0}, d1 = {0,0,0,0};
        float4 d2 = {0,0,0,0}, d3 = {0,0,0,0}, qq = {0,0,0,0};
#pragma unroll
        for (int q = 0; q < 4; ++q) {
            const float4 v = emb4[(size_t)r * 32 + kl + 8 * q];
            FMA4(d0, r0[q], v);
            FMA4(d1, r1[q], v);
            FMA4(d2, r2[q], v);
            FMA4(d3, r3[q], v);
            FMA4(qq, v, v);
        }
        float t0 = hsum4(d0), t1 = hsum4(d1);
        float t2 = hsum4(d2), t3 = hsum4(d3), sqj = hsum4(qq);
#pragma unroll
        for (int off = 1; off < 8; off <<= 1) {
            t0  += __shfl_down(t0, off);
            t1  += __shfl_down(t1, off);
            t2  += __shfl_down(t2, off);
            t3  += __shfl_down(t3, off);
            sqj += __shfl_down(sqj, off);
        }
        if (kl == 0) {
            const int   lr = labels[r];
            const float dA = sqrtf(fmaxf(sq0 + sqj - 2.f * t0, 1e-12f));
            const float dB = sqrtf(fmaxf(sq1 + sqj - 2.f * t1, 1e-12f));
            const float dC = sqrtf(fmaxf(sq2 + sqj - 2.f * t2, 1e-12f));
            const float dD = sqrtf(fmaxf(sq3 + sqj - 2.f * t3, 1e-12f));
            const bool  e0 = (lr == li0), e1 = (lr == li1);
            const bool  e2 = (lr == li2), e3 = (lr == li3);
            drows[0][r] = e0 ? BIGF : dA;   // self has e0 -> excluded too
            drows[1][r] = e1 ? BIGF : dB;
            drows[2][r] = e2 ? BIGF : dC;
            drows[3][r] = e3 ? BIGF : dD;
            if (e0 && r != i0) { int p = atomicAdd(&nposArr[0], 1); pds[0][p] = dA; }
            if (e1 && r != i1) { int p = atomicAdd(&nposArr[1], 1); pds[1][p] = dB; }
            if (e2 && r != i2) { int p = atomicAdd(&nposArr[2], 1); pds[2][p] = dC; }
            if (e3 && r != i3) { int p = atomicAdd(&nposArr[3], 1); pds[3][p] = dD; }
        }
    }
    __syncthreads();

    // ---------------- Phase B: 4 waves per anchor --------------------------
    const int anc  = wave >> 2;             // 0..3
    const int wsub = wave & 3;
    const float* drow = drows[anc];
    const float* pd   = pds[anc];
    const int    npos = nposArr[anc];

    // min over negatives (BIGF is identity); has_neg == (mn < 1e29)
    float mn = BIGF;
#pragma unroll
    for (int kk = 0; kk < BN / 64; ++kk)
        mn = fminf(mn, drow[lane + 64 * kk]);
#pragma unroll
    for (int off = 32; off; off >>= 1)
        mn = fminf(mn, __shfl_xor(mn, off));

    float lsum = 0.f;
    int   lcnt = 0;
    if (mn < 1e29f) {
        for (int p = wsub; p < npos; p += 4) {
            const float dap = pd[p];
            const float hi  = dap + TMARGIN;
            float smax = -BIGF;
#pragma unroll
            for (int kk = 0; kk < BN / 64; ++kk) {
                const float dan = drow[lane + 64 * kk];
                if (dan > dap && dan < hi) smax = fmaxf(smax, dan);
            }
#pragma unroll
            for (int off = 32; off; off >>= 1)
                smax = fmaxf(smax, __shfl_xor(smax, off));
            const float dneg = (smax > -1e29f) ? smax : mn;
            lsum += fmaxf(dap - dneg + TMARGIN, 0.f);
            lcnt += 1;
        }
    }
    if (lane == 0) { wsum[wave] = lsum; wcnt[wave] = lcnt; }
    __syncthreads();

    // one combined partial per block; plain stores (kernel-end flush)
    if (tid == 0) {
        float s = 0.f;
        int   c = 0;
#pragma unroll
        for (int w = 0; w < NW; ++w) { s += wsum[w]; c += wcnt[w]; }
        psum[blockIdx.x] = s;
        pcnt[blockIdx.x] = (float)c;
    }
}

// ---------------------------------------------------------------------------
// Finalize: one wave reduces the 128 partial slots. No LDS, no barriers.
// ---------------------------------------------------------------------------
__global__ __launch_bounds__(64) void finalize_kernel(
        const float* __restrict__ psum,
        const float* __restrict__ pcnt,
        float* __restrict__ out) {
    const int lane = threadIdx.x;
    float s = 0.f, c = 0.f;
#pragma unroll
    for (int i = 0; i < NBLK / 64; ++i) {
        s += psum[lane + 64 * i];
        c += pcnt[lane + 64 * i];
    }
#pragma unroll
    for (int off = 32; off; off >>= 1) {
        s += __shfl_xor(s, off);
        c += __shfl_xor(c, off);
    }
    if (lane == 0)
        out[0] = (c > 0.f) ? (s / fmaxf(c, 1.f)) : 0.f;
}

extern "C" void kernel_launch(void* const* d_in, const int* in_sizes, int n_in,
                              void* d_out, int out_size, void* d_ws, size_t ws_size,
                              hipStream_t stream) {
    const float* emb    = (const float*)d_in[0];
    const int*   labels = (const int*)d_in[1];
    float*       out    = (float*)d_out;
    float*       psum   = (float*)d_ws;        // [128]
    float*       pcnt   = psum + NBLK;         // [128]

    triplet_fused_kernel<<<NBLK, NT, 0, stream>>>(emb, labels, psum, pcnt);
    finalize_kernel<<<1, 64, 0, stream>>>(psum, pcnt, out);
}

// Round 6
// 64.690 us; speedup vs baseline: 1.1228x; 1.0183x over previous
//
#include <hip/hip_runtime.h>

#define BN 512
#define DIM 128
#define TMARGIN 0.3f
#define NT 1024
#define NW 16     // waves per block
#define NBLK 256  // 2 anchors per block, 1 block/CU
#define BIGF 1e30f

#define FMA4(ACC, U, V)                                                \
    ACC.x += U.x * V.x; ACC.y += U.y * V.y;                            \
    ACC.z += U.z * V.z; ACC.w += U.w * V.w;

__device__ __forceinline__ float hsum4(float4 v) {
    return (v.x + v.y) + (v.z + v.w);
}

// ---------------------------------------------------------------------------
// REVERT to round-3 geometry (best measured: 63.9us — 256 blocks x 1024 thr,
// 2 anchors/block). Round-5's 4-anchor/128-block lost (+2us): latency-bound
// kernel -> per-block critical path matters more than aggregate L2 traffic.
//
// ONE change vs round-3: Phase A's two row-iterations are MERGED into a
// single 8-step loop processing both rows (rA, rA+256) together. The 268MB
// per-iteration workspace re-poison evicts emb from L2+L3 (268>256MiB), so
// Phase A loads are HBM-miss (~900cyc; r2 FETCH=1.13MB >> 256KB input).
// Round-3 exposed that latency twice (two sequential 8-load batches);
// merged, all 16 independent loads issue back-to-back -> one exposed stall.
// Per-row FMA/reduce order is bitwise identical to round-3.
//
// Retained: anchors in registers (kl-slice); negative mask folded into drow
// (1e30 sentinel, no labels in Phase B); positive DISTANCES compacted
// inline; plain-store partials + 1-wave finalize (single-dispatch attempts
// all lost: grid.sync +25us r2, contended ticket +9us r4).
// ---------------------------------------------------------------------------
__global__ __launch_bounds__(NT, 4) void triplet_fused_kernel(
        const float* __restrict__ emb,
        const int* __restrict__ labels,
        float* __restrict__ psum,    // [NBLK]
        float* __restrict__ pcnt) {  // [NBLK]
    const int ia   = blockIdx.x;         // anchor A
    const int ib   = blockIdx.x + NBLK;  // anchor B
    const int tid  = threadIdx.x;
    const int lane = tid & 63;
    const int wave = tid >> 6;
    const int rl   = lane >> 2;   // row-in-group 0..15
    const int kl   = lane & 3;    // k-lane 0..3

    __shared__ float drowA[BN], drowB[BN];   // negatives-only distance rows
    __shared__ float pdA[BN], pdB[BN];       // positive distances (compact)
    __shared__ int   nposA, nposB;
    __shared__ float wsum[NW];
    __shared__ int   wcnt[NW];

    const float4* emb4 = (const float4*)emb;
    const int liA = labels[ia];
    const int liB = labels[ib];

    // --- anchor fragments in registers (kl-slice only) --------------------
    float4 ra[8], rb[8];
#pragma unroll
    for (int q = 0; q < 8; ++q) {
        ra[q] = emb4[(size_t)ia * 32 + kl + 4 * q];
        rb[q] = emb4[(size_t)ib * 32 + kl + 4 * q];
    }
    // squared norms: per-thread partial over the kl-slice, then 4-lane sum
    float4 sa = {0,0,0,0}, sb = {0,0,0,0};
#pragma unroll
    for (int q = 0; q < 8; ++q) { FMA4(sa, ra[q], ra[q]); FMA4(sb, rb[q], rb[q]); }
    float sqA = hsum4(sa), sqB = hsum4(sb);
    sqA += __shfl_xor(sqA, 1); sqA += __shfl_xor(sqA, 2);
    sqB += __shfl_xor(sqB, 1); sqB += __shfl_xor(sqB, 2);

    if (tid == 0) { nposA = 0; nposB = 0; }
    __syncthreads();

    // ---------------- Phase A: both rows in ONE pipelined loop ------------
    // 16 waves x 16 rows per half; 4 lanes per row. Rows rA and rA+256
    // processed together so all 16 global loads are independent.
    {
        const int rA = wave * 16 + rl;        // 0..255
        const int rB = rA + 256;              // 256..511
        float4 daA = {0,0,0,0}, dbA = {0,0,0,0}, qqA = {0,0,0,0};
        float4 daB = {0,0,0,0}, dbB = {0,0,0,0}, qqB = {0,0,0,0};
#pragma unroll
        for (int q = 0; q < 8; ++q) {
            const float4 vA = emb4[(size_t)rA * 32 + kl + 4 * q];
            const float4 vB = emb4[(size_t)rB * 32 + kl + 4 * q];
            FMA4(daA, ra[q], vA); FMA4(dbA, rb[q], vA); FMA4(qqA, vA, vA);
            FMA4(daB, ra[q], vB); FMA4(dbB, rb[q], vB); FMA4(qqB, vB, vB);
        }
        float dotAA = hsum4(daA), dotBA = hsum4(dbA), sqjA = hsum4(qqA);
        float dotAB = hsum4(daB), dotBB = hsum4(dbB), sqjB = hsum4(qqB);
        dotAA += __shfl_down(dotAA, 1); dotAA += __shfl_down(dotAA, 2);
        dotBA += __shfl_down(dotBA, 1); dotBA += __shfl_down(dotBA, 2);
        sqjA  += __shfl_down(sqjA, 1);  sqjA  += __shfl_down(sqjA, 2);
        dotAB += __shfl_down(dotAB, 1); dotAB += __shfl_down(dotAB, 2);
        dotBB += __shfl_down(dotBB, 1); dotBB += __shfl_down(dotBB, 2);
        sqjB  += __shfl_down(sqjB, 1);  sqjB  += __shfl_down(sqjB, 2);
        if (kl == 0) {
            // row rA
            {
                const int   lr = labels[rA];
                const float dA = sqrtf(fmaxf(sqA + sqjA - 2.f * dotAA, 1e-12f));
                const float dB = sqrtf(fmaxf(sqB + sqjA - 2.f * dotBA, 1e-12f));
                const bool  eqA = (lr == liA), eqB = (lr == liB);
                drowA[rA] = eqA ? BIGF : dA;   // self has eqA -> excluded too
                drowB[rA] = eqB ? BIGF : dB;
                if (eqA && rA != ia) { int p = atomicAdd(&nposA, 1); pdA[p] = dA; }
                if (eqB && rA != ib) { int p = atomicAdd(&nposB, 1); pdB[p] = dB; }
            }
            // row rB
            {
                const int   lr = labels[rB];
                const float dA = sqrtf(fmaxf(sqA + sqjB - 2.f * dotAB, 1e-12f));
                const float dB = sqrtf(fmaxf(sqB + sqjB - 2.f * dotBB, 1e-12f));
                const bool  eqA = (lr == liA), eqB = (lr == liB);
                drowA[rB] = eqA ? BIGF : dA;
                drowB[rB] = eqB ? BIGF : dB;
                if (eqA && rB != ia) { int p = atomicAdd(&nposA, 1); pdA[p] = dA; }
                if (eqB && rB != ib) { int p = atomicAdd(&nposB, 1); pdB[p] = dB; }
            }
        }
    }
    __syncthreads();

    // ---------------- Phase B: waves 0-7 anchor A, 8-15 anchor B ----------
    const int grp  = wave >> 3;             // 0: A, 1: B
    const int wsub = wave & 7;
    const float* drow = grp ? drowB : drowA;
    const float* pd   = grp ? pdB   : pdA;
    const int    npos = grp ? nposB : nposA;

    // min over negatives (BIGF is identity); has_neg == (mn < 1e29)
    float mn = BIGF;
#pragma unroll
    for (int kk = 0; kk < BN / 64; ++kk)
        mn = fminf(mn, drow[lane + 64 * kk]);
#pragma unroll
    for (int off = 32; off; off >>= 1)
        mn = fminf(mn, __shfl_xor(mn, off));

    float lsum = 0.f;
    int   lcnt = 0;
    if (mn < 1e29f) {
        for (int p = wsub; p < npos; p += 8) {
            const float dap = pd[p];
            const float hi  = dap + TMARGIN;
            float smax = -BIGF;
#pragma unroll
            for (int kk = 0; kk < BN / 64; ++kk) {
                const float dan = drow[lane + 64 * kk];
                if (dan > dap && dan < hi) smax = fmaxf(smax, dan);
            }
#pragma unroll
            for (int off = 32; off; off >>= 1)
                smax = fmaxf(smax, __shfl_xor(smax, off));
            const float dneg = (smax > -1e29f) ? smax : mn;
            lsum += fmaxf(dap - dneg + TMARGIN, 0.f);
            lcnt += 1;
        }
    }
    if (lane == 0) { wsum[wave] = lsum; wcnt[wave] = lcnt; }
    __syncthreads();

    // one combined partial per block; plain stores (kernel-end flush)
    if (tid == 0) {
        float s = 0.f;
        int   c = 0;
#pragma unroll
        for (int w = 0; w < NW; ++w) { s += wsum[w]; c += wcnt[w]; }
        psum[blockIdx.x] = s;
        pcnt[blockIdx.x] = (float)c;
    }
}

// ---------------------------------------------------------------------------
// Finalize: one wave reduces the 256 partial slots. No LDS, no barriers.
// ---------------------------------------------------------------------------
__global__ __launch_bounds__(64) void finalize_kernel(
        const float* __restrict__ psum,
        const float* __restrict__ pcnt,
        float* __restrict__ out) {
    const int lane = threadIdx.x;
    float s = 0.f, c = 0.f;
#pragma unroll
    for (int i = 0; i < NBLK / 64; ++i) {
        s += psum[lane + 64 * i];
        c += pcnt[lane + 64 * i];
    }
#pragma unroll
    for (int off = 32; off; off >>= 1) {
        s += __shfl_xor(s, off);
        c += __shfl_xor(c, off);
    }
    if (lane == 0)
        out[0] = (c > 0.f) ? (s / fmaxf(c, 1.f)) : 0.f;
}

extern "C" void kernel_launch(void* const* d_in, const int* in_sizes, int n_in,
                              void* d_out, int out_size, void* d_ws, size_t ws_size,
                              hipStream_t stream) {
    const float* emb    = (const float*)d_in[0];
    const int*   labels = (const int*)d_in[1];
    float*       out    = (float*)d_out;
    float*       psum   = (float*)d_ws;        // [256]
    float*       pcnt   = psum + NBLK;         // [256]

    triplet_fused_kernel<<<NBLK, NT, 0, stream>>>(emb, labels, psum, pcnt);
    finalize_kernel<<<1, 64, 0, stream>>>(psum, pcnt, out);
}